// Round 13
// baseline (572.260 us; speedup 1.0000x reference)
//
#include <hip/hip_runtime.h>
#include <stdint.h>

#define R_NUM 4096
#define D_DIM 64
#define DEG_N 6
#define MF 8
#define NSHARD 16
#define SHARD_ITEMS 4096   // 65536 (region,slice) items / 16 shards
#define FB_COEF 0.035355339059327376f  // FB_ALPHA * FB_SCALE = 0.1/sqrt(8)

typedef float f4v __attribute__((ext_vector_type(4)));

// R13: persistent waves + sharded atomic work queue.
// Evidence: R9 static-persistent (46.2) is tail-bound (Binomial(96,.5)
// per-consumer, sigma/mu=10%); R11/R12 block-per-region (50.1/47.0) pay
// ~12us of per-block ramp. This kernel combines R8's deep per-wave pipeline
// (95% streaming BW on uniform work) with dynamic balance:
//  - work item = (region r, slices 4c..4c+3): 16384 items on 16 atomic
//    shards (d_ws counters, ~1k pops each, ~35ns spacing).
//  - 2048 persistent waves (grid 256 x 512thr, 8 waves/CU): ~8 items/wave
//    -> makespan ~= ideal + 1 item. Waves drain their shard, then steal.
//  - per item: ONE region prologue (weights by lanes 0..5 + shfl bcast);
//    H float4s loaded once (slice-invariant), reused 4x; 12KB of W slices
//    streamed with ping-pong 6-load nt clusters (<=12 loads in flight).
//  - next pop issued before the stream so atomic latency hides under it.
//  - mask-skip: w==0 edges' panels never fetched (~203 MB mandatory).
// Queue counters are zeroed via hipMemsetAsync each launch (graph-safe);
// output is deterministic regardless of which wave pops which item.
__launch_bounds__(512, 2)
__global__ void router_kernel(const float* __restrict__ H,
                              const void* __restrict__ mask_raw,
                              const float* __restrict__ coords,
                              const float* __restrict__ W_edges,
                              const float* __restrict__ W_reg,
                              const float* __restrict__ beta_cos,
                              const float* __restrict__ beta_sin,
                              const int* __restrict__ src,
                              unsigned int* __restrict__ qcnt,
                              float* __restrict__ out) {
  const int t    = threadIdx.x;
  const int lane = t & 63;
  const int gwid = (blockIdx.x << 3) + (t >> 6);
  const int j0   = (lane & 15) << 2;

  // ---- per-wave mask-dtype detection (once; first 1 KB is safe to read
  // under every candidate encoding). flag: 0=bool8,1=int32,2=int64,3=f32
  const uint32_t* mw = (const uint32_t*)mask_raw;
  bool int01 = true, f01 = true, oddz = true, even1 = false;
#pragma unroll
  for (int i = 0; i < 4; ++i) {
    const int idx = lane + 64 * i;
    const uint32_t v = mw[idx];
    int01 = int01 && (v <= 1u);
    f01   = f01 && (v == 0u || v == 0x3f800000u);
    if (lane & 1) oddz = oddz && (v == 0u);
    else          even1 = even1 || (v == 1u);
  }
  const bool all_int01 = (__ballot(int01) == ~0ULL);
  const bool all_f01   = (__ballot(f01)   == ~0ULL);
  const bool all_oddz  = (__ballot(!oddz) == 0ULL);
  const bool any_even1 = (__ballot(even1) != 0ULL);
  int mflag = 0;
  if (all_int01)    mflag = (all_oddz && any_even1) ? 2 : 1;
  else if (all_f01) mflag = 3;

  const int s0 = gwid & (NSHARD - 1);
  for (int sh = 0; sh < NSHARD; ++sh) {
    const int s = (s0 + sh) & (NSHARD - 1);
    int il = 0;
    if (lane == 0) il = (int)atomicAdd(&qcnt[s], 4u);
    il = __shfl(il, 0);
    while (il < SHARD_ITEMS) {
      const int item = s * SHARD_ITEMS + il;
      const int r    = item >> 4;
      const int w0   = item & 15;        // 0,4,8,12 (4-aligned, one region)

      // ---- pop next item early: atomic latency hides under this batch
      int iln = 0;
      if (lane == 0) iln = (int)atomicAdd(&qcnt[s], 4u);
      iln = __shfl(iln, 0);

      // ---- region prologue: 6 edge weights (lanes 0..5), shfl broadcast
      float wq = 0.f; int sq = 0;
      if (lane < DEG_N) {
        const int e = r * DEG_N + lane;
        const int sv_ = src[e];
        sq = sv_;
        const float dx = coords[2 * r]     - coords[2 * sv_];
        const float dy = coords[2 * r + 1] - coords[2 * sv_ + 1];
        float b = 0.f;
#pragma unroll
        for (int m = 0; m < MF; ++m) {
          const float S = dx * W_reg[2 * m] + dy * W_reg[2 * m + 1];
          float sn, cs;
          __sincosf(S, &sn, &cs);
          b += cs * beta_cos[m] + sn * beta_sin[m];
        }
        bool mv;
        if (mflag == 1)      mv = ((const int*)mask_raw)[sq] != 0;
        else if (mflag == 2) mv = ((const long long*)mask_raw)[sq] != 0;
        else if (mflag == 3) mv = ((const float*)mask_raw)[sq] != 0.f;
        else                 mv = ((const uint8_t*)mask_raw)[sq] != 0;
        wq = mv ? fmaf(FB_COEF, b, 1.0f) : 0.f;
      }
      float ww[DEG_N]; int ss[DEG_N];
#pragma unroll
      for (int k = 0; k < DEG_N; ++k) {
        ww[k] = __shfl(wq, k);
        ss[k] = __shfl(sq, k);
      }

      // ---- H float4s: slice-invariant, load once per batch (L1/L2) ----
      float4 hv[DEG_N];
#pragma unroll
      for (int k = 0; k < DEG_N; ++k)
        if (ww[k] != 0.f)
          hv[k] = *reinterpret_cast<const float4*>(&H[ss[k] * D_DIM + j0]);

      const float* __restrict__ Wb =
          W_edges + (size_t)r * (DEG_N * D_DIM * D_DIM);

      f4v RA[DEG_N], RB[DEG_N];
      // slice SLC: floats [SLC*256, SLC*256+256) of each active edge matrix;
      // lane reads float4 at + lane*4 -> wave-contiguous 1KB nt burst.
#define LOADS(SLC, RG)                                                       \
  _Pragma("unroll") for (int k = 0; k < DEG_N; ++k)                          \
    if (ww[k] != 0.f)                                                        \
      RG[k] = __builtin_nontemporal_load(reinterpret_cast<const f4v*>(       \
          Wb + k * (D_DIM * D_DIM) + (SLC) * 256 + lane * 4));
      // row of lane within slice SLC: 4*SLC + (lane>>4); cols j0..j0+3
#define CONSUME(SLC, RG)                                                     \
  {                                                                          \
    float p = 0.f;                                                           \
    _Pragma("unroll") for (int k = 0; k < DEG_N; ++k)                        \
      if (ww[k] != 0.f)                                                      \
        p = fmaf(ww[k],                                                      \
                 RG[k].x * hv[k].x + RG[k].y * hv[k].y +                     \
                 RG[k].z * hv[k].z + RG[k].w * hv[k].w, p);                  \
    _Pragma("unroll") for (int off = 1; off < 16; off <<= 1)                 \
      p += __shfl_xor(p, off);                                               \
    const float p0 = __shfl(p, 0);                                           \
    const float p1 = __shfl(p, 16);                                          \
    const float p2 = __shfl(p, 32);                                          \
    const float p3 = __shfl(p, 48);                                          \
    if (lane == 0)                                                           \
      *reinterpret_cast<float4*>(&out[r * D_DIM + (SLC) * 4]) =              \
          make_float4(p0, p1, p2, p3);                                       \
  }
      LOADS(w0 + 0, RA)
      LOADS(w0 + 1, RB)
      CONSUME(w0 + 0, RA)
      LOADS(w0 + 2, RA)
      CONSUME(w0 + 1, RB)
      LOADS(w0 + 3, RB)
      CONSUME(w0 + 2, RA)
      CONSUME(w0 + 3, RB)
#undef LOADS
#undef CONSUME

      il = iln;
    }
  }
}

extern "C" void kernel_launch(void* const* d_in, const int* in_sizes, int n_in,
                              void* d_out, int out_size, void* d_ws, size_t ws_size,
                              hipStream_t stream) {
  const float* H        = (const float*)d_in[0];
  const void*  mask     = d_in[1];
  const float* coords   = (const float*)d_in[2];
  const float* W_edges  = (const float*)d_in[3];
  const float* W_reg    = (const float*)d_in[4];
  const float* beta_cos = (const float*)d_in[5];
  const float* beta_sin = (const float*)d_in[6];
  const int*   src      = (const int*)d_in[7];
  // d_in[8] (dst) is structurally repeat(arange(R), 6); not needed.

  // zero the 16 queue counters every call (graph-safe async memset;
  // harness poisons d_ws once and never re-poisons between replays).
  hipMemsetAsync(d_ws, 0, NSHARD * sizeof(unsigned int), stream);
  router_kernel<<<256, 512, 0, stream>>>(H, mask, coords, W_edges, W_reg,
                                         beta_cos, beta_sin, src,
                                         (unsigned int*)d_ws, (float*)d_out);
}

// Round 14
// 81.519 us; speedup vs baseline: 7.0199x; 7.0199x over previous
//
#include <hip/hip_runtime.h>
#include <stdint.h>

#define R_NUM 4096
#define D_DIM 64
#define DEG_N 6
#define MF 8
#define NB 256
#define FB_COEF 0.035355339059327376f  // FB_ALPHA * FB_SCALE = 0.1/sqrt(8)

typedef float f4v __attribute__((ext_vector_type(4)));

// ---------------------------------------------------------------------------
// R14: two-phase balanced static schedule. R13's atomic queue showed
// same-address cross-XCD atomics cost ~0.5us each (572us total!). Static
// schedules (R9) carry a Binomial(96,0.5) straggler tail (+28%). Fix: spend
// ~5us computing the EXACT balance: per-region active-edge counts -> prefix
// sum -> 256 contiguous spans of equal active work (+-6 edges). No atomics
// in the hot kernel, no tail, sequential W panels within a span.
// ---------------------------------------------------------------------------

// mask-dtype detection (shared by both kernels, wave-level):
//  flag: 0 = 1-byte bool, 1 = int32, 2 = int64, 3 = float32
__device__ __forceinline__ int detect_mask(const void* mask_raw, int lane) {
  const uint32_t* mw = (const uint32_t*)mask_raw;
  bool int01 = true, f01 = true, oddz = true, even1 = false;
#pragma unroll
  for (int i = 0; i < 4; ++i) {
    const int idx = lane + 64 * i;        // parity of idx == parity of lane
    const uint32_t v = mw[idx];
    int01 = int01 && (v <= 1u);
    f01   = f01 && (v == 0u || v == 0x3f800000u);
    if (lane & 1) oddz = oddz && (v == 0u);
    else          even1 = even1 || (v == 1u);
  }
  const bool all_int01 = (__ballot(int01) == ~0ULL);
  const bool all_f01   = (__ballot(f01)   == ~0ULL);
  const bool all_oddz  = (__ballot(!oddz) == 0ULL);
  const bool any_even1 = (__ballot(even1) != 0ULL);
  int mflag = 0;
  if (all_int01)    mflag = (all_oddz && any_even1) ? 2 : 1;
  else if (all_f01) mflag = 3;
  return mflag;
}

__device__ __forceinline__ bool mask_at(const void* mask_raw, int mflag, int s) {
  if (mflag == 1) return ((const int*)mask_raw)[s] != 0;
  if (mflag == 2) return ((const long long*)mask_raw)[s] != 0;
  if (mflag == 3) return ((const float*)mask_raw)[s] != 0.f;
  return ((const uint8_t*)mask_raw)[s] != 0;
}

// ---- phase 1: build the balanced schedule (1 block, ~5us) ----
__launch_bounds__(1024)
__global__ void schedule_kernel(const void* __restrict__ mask_raw,
                                const int* __restrict__ src,
                                int* __restrict__ bound) {
  const int t    = threadIdx.x;
  const int lane = t & 63;
  __shared__ int pref[R_NUM];       // inclusive prefix of per-region counts
  __shared__ int tsum[1024];
  __shared__ int s_mflag;

  if (t < 64) {
    const int f = detect_mask(mask_raw, lane);
    if (lane == 0) s_mflag = f;
  }
  __syncthreads();
  const int mflag = s_mflag;

  // per-region active-edge counts (4 regions/thread)
  int c[4], cnt4 = 0;
#pragma unroll
  for (int i = 0; i < 4; ++i) {
    const int r = t * 4 + i;
    int cc = 0;
#pragma unroll
    for (int k = 0; k < DEG_N; ++k)
      cc += mask_at(mask_raw, mflag, src[r * DEG_N + k]) ? 1 : 0;
    c[i] = cc; cnt4 += cc;
  }
  tsum[t] = cnt4;
  __syncthreads();
  // Hillis-Steele inclusive scan over the 1024 thread sums
  for (int off = 1; off < 1024; off <<= 1) {
    const int v = (t >= off) ? tsum[t - off] : 0;
    __syncthreads();
    tsum[t] += v;
    __syncthreads();
  }
  int run = tsum[t] - cnt4;
#pragma unroll
  for (int i = 0; i < 4; ++i) { run += c[i]; pref[t * 4 + i] = run; }
  __syncthreads();
  const int total = tsum[1023];

  // bound[b] = first r with pref[r] > total*b/NB  (bound[0]=0, bound[NB]=R)
  if (t <= NB) {
    int lo;
    if (t == 0)        lo = 0;
    else if (t == NB)  lo = R_NUM;
    else {
      const long long target = ((long long)total * t) / NB;
      int a = 0, bb = R_NUM;
      while (a < bb) {
        const int m = (a + bb) >> 1;
        if ((long long)pref[m] > target) bb = m; else a = m + 1;
      }
      lo = a;
    }
    bound[t] = lo;
  }
}

// ---- phase 2: streaming router over balanced spans ----
// Block b processes regions [bound[b], bound[b+1]). Wave w owns output rows
// 4w..4w+3 of every region: thread t reads float4 at flat offset 4t of each
// active 64x64 edge matrix (wave-contiguous 1KB nt burst per edge-slice).
// Per-wave prologue (lanes 0..5 sincos + shfl bcast; no LDS, no barrier),
// double-buffered W with next-region prefetch issued before consume.
__launch_bounds__(1024, 4)
__global__ void router_kernel(const float* __restrict__ H,
                              const void* __restrict__ mask_raw,
                              const float* __restrict__ coords,
                              const float* __restrict__ W_edges,
                              const float* __restrict__ W_reg,
                              const float* __restrict__ beta_cos,
                              const float* __restrict__ beta_sin,
                              const int* __restrict__ src,
                              const int* __restrict__ bound,
                              float* __restrict__ out) {
  const int t    = threadIdx.x;
  const int lane = t & 63;
  const int wid  = t >> 6;
  const int j0   = (lane & 15) << 2;

  const int rs = bound[blockIdx.x];
  const int re = bound[blockIdx.x + 1];
  if (rs >= re) return;

  const int mflag = detect_mask(mask_raw, lane);
  const size_t PANEL = (size_t)DEG_N * D_DIM * D_DIM;

  // per-wave region prologue -> wave-uniform ww/ss
#define PROLOGUE(RR, WWA, SSA)                                               \
  {                                                                          \
    float wq = 0.f; int sq = 0;                                              \
    if (lane < DEG_N) {                                                      \
      const int e  = (RR) * DEG_N + lane;                                    \
      const int sv = src[e];                                                 \
      sq = sv;                                                               \
      const float dx = coords[2 * (RR)]     - coords[2 * sv];                \
      const float dy = coords[2 * (RR) + 1] - coords[2 * sv + 1];            \
      float bacc = 0.f;                                                      \
      _Pragma("unroll") for (int m = 0; m < MF; ++m) {                       \
        const float S = dx * W_reg[2 * m] + dy * W_reg[2 * m + 1];           \
        float sn, cs;                                                        \
        __sincosf(S, &sn, &cs);                                              \
        bacc += cs * beta_cos[m] + sn * beta_sin[m];                         \
      }                                                                      \
      wq = mask_at(mask_raw, mflag, sq) ? fmaf(FB_COEF, bacc, 1.0f) : 0.f;   \
    }                                                                        \
    _Pragma("unroll") for (int k = 0; k < DEG_N; ++k) {                      \
      WWA[k] = __shfl(wq, k);                                                \
      SSA[k] = __shfl(sq, k);                                                \
    }                                                                        \
  }

#define WLOADS(RR, WWA, RG)                                                  \
  {                                                                          \
    const float* __restrict__ Wp = W_edges + (size_t)(RR) * PANEL;           \
    _Pragma("unroll") for (int k = 0; k < DEG_N; ++k) {                      \
      RG[k] = (f4v)(0.f);                                                    \
      if (WWA[k] != 0.f)                                                     \
        RG[k] = __builtin_nontemporal_load(reinterpret_cast<const f4v*>(     \
            Wp + k * (D_DIM * D_DIM) + t * 4));                              \
    }                                                                        \
  }

  float cww[DEG_N]; int css[DEG_N]; f4v cur[DEG_N], nxt[DEG_N];
  PROLOGUE(rs, cww, css)
  WLOADS(rs, cww, cur)

  for (int r = rs; r < re; ++r) {
    float nww[DEG_N]; int nss[DEG_N];
    const bool more = (r + 1 < re);
    if (more) {
      PROLOGUE(r + 1, nww, nss)
      WLOADS(r + 1, nww, nxt)
    }

    // consume current region
    float p = 0.f;
#pragma unroll
    for (int k = 0; k < DEG_N; ++k) {
      if (cww[k] != 0.f) {
        const float4 hv =
            *reinterpret_cast<const float4*>(&H[css[k] * D_DIM + j0]);
        p = fmaf(cww[k],
                 cur[k].x * hv.x + cur[k].y * hv.y +
                 cur[k].z * hv.z + cur[k].w * hv.w,
                 p);
      }
    }
#pragma unroll
    for (int off = 1; off < 16; off <<= 1) p += __shfl_xor(p, off);
    const float p0 = __shfl(p, 0);
    const float p1 = __shfl(p, 16);
    const float p2 = __shfl(p, 32);
    const float p3 = __shfl(p, 48);
    if (lane == 0) {
      *reinterpret_cast<float4*>(&out[r * D_DIM + 4 * wid]) =
          make_float4(p0, p1, p2, p3);
    }

    if (more) {
#pragma unroll
      for (int k = 0; k < DEG_N; ++k) {
        cur[k] = nxt[k]; cww[k] = nww[k]; css[k] = nss[k];
      }
    }
  }
#undef PROLOGUE
#undef WLOADS
}

extern "C" void kernel_launch(void* const* d_in, const int* in_sizes, int n_in,
                              void* d_out, int out_size, void* d_ws, size_t ws_size,
                              hipStream_t stream) {
  const float* H        = (const float*)d_in[0];
  const void*  mask     = d_in[1];
  const float* coords   = (const float*)d_in[2];
  const float* W_edges  = (const float*)d_in[3];
  const float* W_reg    = (const float*)d_in[4];
  const float* beta_cos = (const float*)d_in[5];
  const float* beta_sin = (const float*)d_in[6];
  const int*   src      = (const int*)d_in[7];
  // d_in[8] (dst) is structurally repeat(arange(R), 6); not needed.
  int* bound = (int*)d_ws;   // 257 ints, rewritten every call (deterministic)

  schedule_kernel<<<1, 1024, 0, stream>>>(mask, src, bound);
  router_kernel<<<NB, 1024, 0, stream>>>(H, mask, coords, W_edges, W_reg,
                                         beta_cos, beta_sin, src, bound,
                                         (float*)d_out);
}

// Round 15
// 46.289 us; speedup vs baseline: 12.3629x; 1.7611x over previous
//
#include <hip/hip_runtime.h>
#include <stdint.h>

#define R_NUM 4096
#define D_DIM 64
#define DEG_N 6
#define MF 8
#define GRID 256                 // one persistent block per CU
#define NR (R_NUM / GRID)        // 16 regions per block
#define FB_COEF 0.035355339059327376f  // FB_ALPHA * FB_SCALE = 0.1/sqrt(8)

typedef float f4v __attribute__((ext_vector_type(4)));

// R15 = R9 restored verbatim (best measured: 46.2us).
// Session evidence: static persistent (this, 46.2) / barrier-free blocks
// (47.0) / barriered blocks (50.1) / wave-decorrelated (50.9) / two-phase
// balanced spans (81.5, VGPR collapse) / atomic queue (572, cross-XCD
// same-line atomics ~0.5us each). Four distinct well-pipelined structures
// converge at 46-50us ~= 4.4-4.7 TB/s effective on ~205 MB of mask-skipped
// (gappy) panel streaming -> empirical floor for this access mix.
__launch_bounds__(1024, 4)
__global__ void router_kernel(const float* __restrict__ H,
                              const void* __restrict__ mask_raw,
                              const float* __restrict__ coords,
                              const float* __restrict__ W_edges,
                              const float* __restrict__ W_reg,
                              const float* __restrict__ beta_cos,
                              const float* __restrict__ beta_sin,
                              const int* __restrict__ src,
                              float* __restrict__ out) {
  const int r0   = blockIdx.x;
  const int t    = threadIdx.x;
  const int lane = t & 63;
  const int wid  = t >> 6;          // wave id 0..15 -> output rows 4w..4w+3
  const int j0   = (t & 15) << 2;   // starting col of this lane's float4

  // ---- per-wave mask-dtype detection over the first 256 words (1 KB;
  // safe under every candidate encoding since the bool buffer is >= 4 KB).
  //  flag: 0 = 1-byte bool, 1 = int32, 2 = int64, 3 = float32
  const uint32_t* mw = (const uint32_t*)mask_raw;
  bool int01 = true, f01 = true, oddz = true, even1 = false;
#pragma unroll
  for (int i = 0; i < 4; ++i) {
    const int idx = lane + 64 * i;        // parity of idx == parity of lane
    const uint32_t v = mw[idx];
    int01 = int01 && (v <= 1u);
    f01   = f01 && (v == 0u || v == 0x3f800000u);
    if (lane & 1) oddz = oddz && (v == 0u);
    else          even1 = even1 || (v == 1u);
  }
  const bool all_int01 = (__ballot(int01) == ~0ULL);
  const bool all_f01   = (__ballot(f01)   == ~0ULL);
  const bool all_oddz  = (__ballot(!oddz) == 0ULL);
  const bool any_even1 = (__ballot(even1) != 0ULL);
  int mflag = 0;
  if (all_int01)    mflag = (all_oddz && any_even1) ? 2 : 1;
  else if (all_f01) mflag = 3;

  // ---- upfront edge weights: local edge ids 0..95; lane covers {lane,
  // lane+64}. li -> (it = li/6, k = li%6) -> region r0+it*GRID, edge k.
  float wa = 0.f, wb = 0.f;
  int   sa = 0,   sb = 0;
#define CALC_EDGE(li, wout, sout)                                            \
  if ((li) < DEG_N * NR) {                                                   \
    const int it = (li) / DEG_N;                                             \
    const int k  = (li) % DEG_N;                                             \
    const int rr = r0 + it * GRID;                                           \
    const int e  = rr * DEG_N + k;                                           \
    const int s  = src[e];                                                   \
    sout = s;                                                                \
    const float dx = coords[2 * rr]     - coords[2 * s];                     \
    const float dy = coords[2 * rr + 1] - coords[2 * s + 1];                 \
    float b = 0.f;                                                           \
    _Pragma("unroll") for (int m = 0; m < MF; ++m) {                         \
      const float S = dx * W_reg[2 * m] + dy * W_reg[2 * m + 1];             \
      float sv, cv;                                                          \
      __sincosf(S, &sv, &cv);                                                \
      b += cv * beta_cos[m] + sv * beta_sin[m];                              \
    }                                                                        \
    bool mv;                                                                 \
    if (mflag == 1)      mv = ((const int*)mask_raw)[s] != 0;                \
    else if (mflag == 2) mv = ((const long long*)mask_raw)[s] != 0;          \
    else if (mflag == 3) mv = ((const float*)mask_raw)[s] != 0.f;            \
    else                 mv = ((const uint8_t*)mask_raw)[s] != 0;            \
    wout = mv ? fmaf(FB_COEF, b, 1.0f) : 0.f;                                \
  }
  CALC_EDGE(lane,      wa, sa)
  CALC_EDGE(lane + 64, wb, sb)
#undef CALC_EDGE

  // e is compile-time static at every use site -> wa/wb select and shfl
  // source lane are static.
#define UNPACK(itc, wout, sout)                                              \
  _Pragma("unroll") for (int k = 0; k < DEG_N; ++k) {                        \
    const int e = (itc) * DEG_N + k;                                         \
    wout[k] = __shfl(e < 64 ? wa : wb, e & 63);                              \
    sout[k] = __shfl(e < 64 ? sa : sb, e & 63);                              \
  }

  const size_t PANEL = (size_t)DEG_N * D_DIM * D_DIM;

  // ---- preload region r0's W panel (active edges only) ----
  float cw[DEG_N]; int cs[DEG_N];
  UNPACK(0, cw, cs)
  f4v cur[DEG_N], nxt[DEG_N];
#pragma unroll
  for (int k = 0; k < DEG_N; ++k) { cur[k] = (f4v)(0.f); nxt[k] = (f4v)(0.f); }
  {
    const float* __restrict__ Wp = W_edges + (size_t)r0 * PANEL;
#pragma unroll
    for (int k = 0; k < DEG_N; ++k)
      if (cw[k] != 0.f)
        cur[k] = __builtin_nontemporal_load(
            reinterpret_cast<const f4v*>(Wp + k * (D_DIM * D_DIM) + t * 4));
  }

#pragma unroll
  for (int it = 0; it < NR; ++it) {
    const int r = r0 + it * GRID;

    // 1) issue next region's W prefetches (active edges only)
    float nw[DEG_N]; int ns[DEG_N];
#pragma unroll
    for (int k = 0; k < DEG_N; ++k) { nw[k] = 0.f; ns[k] = 0; }
    if (it + 1 < NR) {
      UNPACK(it + 1, nw, ns)
      const float* __restrict__ Wp = W_edges + (size_t)(r + GRID) * PANEL;
#pragma unroll
      for (int k = 0; k < DEG_N; ++k) {
        nxt[k] = (f4v)(0.f);
        if (nw[k] != 0.f)
          nxt[k] = __builtin_nontemporal_load(
              reinterpret_cast<const f4v*>(Wp + k * (D_DIM * D_DIM) + t * 4));
      }
    }

    // 2) fma chain on current region (skips are wave-uniform exec branches)
    float p = 0.f;
#pragma unroll
    for (int k = 0; k < DEG_N; ++k) {
      if (cw[k] != 0.f) {
        const float4 hv =
            *reinterpret_cast<const float4*>(&H[cs[k] * D_DIM + j0]);
        p = fmaf(cw[k],
                 cur[k].x * hv.x + cur[k].y * hv.y +
                 cur[k].z * hv.z + cur[k].w * hv.w,
                 p);
      }
    }

    // 3) reduce across the 16 lanes owning each output row
#pragma unroll
    for (int off = 1; off < 16; off <<= 1) p += __shfl_xor(p, off);
    const float p0 = __shfl(p, 0);
    const float p1 = __shfl(p, 16);
    const float p2 = __shfl(p, 32);
    const float p3 = __shfl(p, 48);
    if (lane == 0) {
      *reinterpret_cast<float4*>(&out[r * D_DIM + 4 * wid]) =
          make_float4(p0, p1, p2, p3);
    }

    // 4) rotate double buffer (all indices static under full unroll)
#pragma unroll
    for (int k = 0; k < DEG_N; ++k) {
      cur[k] = nxt[k]; cw[k] = nw[k]; cs[k] = ns[k];
    }
  }
#undef UNPACK
}

extern "C" void kernel_launch(void* const* d_in, const int* in_sizes, int n_in,
                              void* d_out, int out_size, void* d_ws, size_t ws_size,
                              hipStream_t stream) {
  const float* H        = (const float*)d_in[0];
  const void*  mask     = d_in[1];
  const float* coords   = (const float*)d_in[2];
  const float* W_edges  = (const float*)d_in[3];
  const float* W_reg    = (const float*)d_in[4];
  const float* beta_cos = (const float*)d_in[5];
  const float* beta_sin = (const float*)d_in[6];
  const int*   src      = (const int*)d_in[7];
  // d_in[8] (dst) is structurally repeat(arange(R), 6); not needed.

  router_kernel<<<GRID, 1024, 0, stream>>>(H, mask, coords, W_edges, W_reg,
                                           beta_cos, beta_sin, src,
                                           (float*)d_out);
}